// Round 24
// baseline (110.265 us; speedup 1.0000x reference)
//
#include <hip/hip_runtime.h>
#include <math.h>

// Problem constants (SelfAttention: b=2, d=1024, s=2048, h=16, hd=64)
#define B_  2
#define D_  1024
#define S_  2048
#define H_  16
#define HD_ 64
#define D3_ 3072
#define M_  4096   // B_*S_

typedef __attribute__((ext_vector_type(8))) short short8;
typedef __attribute__((ext_vector_type(4))) float float4v;

__device__ __forceinline__ short f2bf(float f) {
    unsigned u = __builtin_bit_cast(unsigned, f);
    unsigned r = (u + 0x7FFFu + ((u >> 16) & 1u)) >> 16;   // RNE
    return (short)r;
}

__device__ __forceinline__ unsigned cvt_pk_bf16(float lo, float hi) {
    unsigned r;
    asm("v_cvt_pk_bf16_f32 %0, %1, %2" : "=v"(r) : "v"(lo), "v"(hi));
    return r;
}

__device__ __forceinline__ float fast_exp2(float x) {
    float r;
    asm("v_exp_f32 %0, %1" : "=v"(r) : "v"(x));
    return r;
}

#define GLD16(gsrc, ldst)                                                      \
    __builtin_amdgcn_global_load_lds(                                          \
        (const __attribute__((address_space(1))) void*)(gsrc),                 \
        (__attribute__((address_space(3))) void*)(ldst), 16, 0, 0)

// ---------- merged transpose + fp32->bf16 convert for x, W1, W2 (R16-exact) ----
__global__ __launch_bounds__(256) void transpose_cvt_all(const float* __restrict__ x,
                                                         short* __restrict__ xt,
                                                         const float* __restrict__ W1,
                                                         short* __restrict__ W1t,
                                                         const float* __restrict__ W2,
                                                         short* __restrict__ W2t) {
    __shared__ short t[64][66];          // +2 pad: write-side reads are 2-way only
    const int bid = (int)blockIdx.x;
    const float* in;
    short* out;
    int C, R, rb, cb;
    if (bid < 1024) {
        const int z = bid >> 9, tt = bid & 511;
        R = D_; C = S_;
        cb = tt & 31; rb = tt >> 5;
        in = x + (size_t)z * D_ * S_;
        out = xt + (size_t)z * D_ * S_;
    } else if (bid < 1792) {
        const int tt = bid - 1024;
        R = D_; C = D3_;
        cb = tt % 48; rb = tt / 48;
        in = W1; out = W1t;
    } else {
        const int tt = bid - 1792;
        R = D_; C = D_;
        cb = tt & 15; rb = tt >> 4;
        in = W2; out = W2t;
    }
    const int r0 = rb * 64, c0 = cb * 64;
    const int tx = threadIdx.x & 31, ty = threadIdx.x >> 5;
    #pragma unroll
    for (int i = ty; i < 64; i += 8) {
        const float2 v = *(const float2*)&in[(size_t)(r0 + i) * C + c0 + tx * 2];
        t[i][tx * 2]     = f2bf(v.x);
        t[i][tx * 2 + 1] = f2bf(v.y);
    }
    __syncthreads();
    #pragma unroll
    for (int j = ty; j < 64; j += 8) {
        short2 v;
        v.x = t[tx * 2][j];
        v.y = t[tx * 2 + 1][j];
        *(short2*)&out[(size_t)(c0 + j) * R + r0 + tx * 2] = v;
    }
}

// ---------- MFMA GEMM core: 8 waves, BK=64 (half the barrier-drain pairs) ----
// [128][64] LDS tiles, attn-proven 8-chunk involution (ch ^ (row&7)): staging
// uses inverse-swizzled global source + linear LDS dest; reads apply same XOR.
// 4 GLD16/thread per K-step (vs R10's failed 8 at 4 waves); 2 barriers / 64-K.
__device__ __forceinline__ void gemm_core8(const short* __restrict__ A,
                                           const short* __restrict__ Bt,
                                           int m0, int n0,
                                           short* As, short* Bs,
                                           float4v acc[2][4]) {
    const int tid = threadIdx.x;
    const int lane = tid & 63, w = tid >> 6;                 // 0..7
    const int wr = (w >> 1) * 32, wc = (w & 1) * 64;
    const int rr = lane & 15, hi4 = lane >> 4;
    for (int k0 = 0; k0 < 1024; k0 += 64) {
        #pragma unroll
        for (int j = 0; j < 2; ++j) {
            const int g = j * 512 + tid;                     // 1024 chunks of 8 shorts
            const int r = g >> 3, c = g & 7;
            const int co = (c ^ (r & 7)) << 3;
            GLD16(A  + (size_t)(m0 + r) * 1024 + k0 + co, As + g * 8);
            GLD16(Bt + (size_t)(n0 + r) * 1024 + k0 + co, Bs + g * 8);
        }
        __syncthreads();
        #pragma unroll
        for (int ks = 0; ks < 2; ++ks) {
            short8 a[2], b[4];
            #pragma unroll
            for (int m = 0; m < 2; ++m) {
                const int row = wr + m * 16 + rr;
                const int ch = ks * 4 + hi4;
                a[m] = *(const short8*)&As[row * 64 + ((ch ^ (row & 7)) << 3)];
            }
            #pragma unroll
            for (int n = 0; n < 4; ++n) {
                const int row = wc + n * 16 + rr;
                const int ch = ks * 4 + hi4;
                b[n] = *(const short8*)&Bs[row * 64 + ((ch ^ (row & 7)) << 3)];
            }
            #pragma unroll
            for (int m = 0; m < 2; ++m)
                #pragma unroll
                for (int n = 0; n < 4; ++n)
                    acc[m][n] = __builtin_amdgcn_mfma_f32_16x16x32_bf16(a[m], b[n], acc[m][n], 0, 0, 0);
        }
        __syncthreads();
    }
}

// ---------- GEMM1: qkv = xt @ W1t^T; XCD-rectangle swizzle; 8-wave BK=64 ----
__global__ __launch_bounds__(512) void gemm_qkv_mfma(const short* __restrict__ xt,
                                                     const short* __restrict__ W1t,
                                                     short* __restrict__ q,
                                                     short* __restrict__ kk,
                                                     short* __restrict__ vt) {
    __shared__ short As[128 * 64], Bs[128 * 64];
    float4v acc[2][4];
    #pragma unroll
    for (int m = 0; m < 2; ++m)
        #pragma unroll
        for (int n = 0; n < 4; ++n) acc[m][n] = (float4v){0.f, 0.f, 0.f, 0.f};
    const int bid = (int)blockIdx.x;
    const int xcd = bid & 7, r = bid >> 3;        // r in 0..95
    const int mt = (xcd & 3) * 8 + (r & 7);       // m-tile 0..31
    const int nt = (xcd >> 2) * 12 + (r >> 3);    // n-tile 0..23
    const int m0 = mt * 128, n0 = nt * 128;
    gemm_core8(xt, W1t, m0, n0, As, Bs, acc);
    const int lane = threadIdx.x & 63, w = threadIdx.x >> 6;
    const int wr = (w >> 1) * 32, wc = (w & 1) * 64;
    const float qscale = 0.125f * 1.44269504f;   // fold softmax scale*log2(e) into q
    #pragma unroll
    for (int n = 0; n < 4; ++n) {
        const int gcol = n0 + wc + n * 16 + (lane & 15);
        const int which = gcol >> 10, hh = (gcol >> 6) & 15, hd = gcol & 63;
        #pragma unroll
        for (int m = 0; m < 2; ++m) {
            #pragma unroll
            for (int ri = 0; ri < 4; ++ri) {
                const int grow = m0 + wr + m * 16 + (lane >> 4) * 4 + ri;
                const int bb = grow >> 11, ss = grow & (S_ - 1);
                float av = acc[m][n][ri];
                if (which == 0) av *= qscale;
                const short v = f2bf(av);
                if (which == 0)      q [((size_t)(bb * H_ + hh) * S_ + ss) * HD_ + hd] = v;
                else if (which == 1) kk[((size_t)(bb * H_ + hh) * S_ + ss) * HD_ + hd] = v;
                else                 vt[((size_t)(bb * H_ + hh) * HD_ + hd) * S_ + ss] = v;
            }
        }
    }
}

// ---------- Flash attention (R23-exact): paired tiles + XCD pin + interleave ----
__global__ __launch_bounds__(256) void attn_mfma(const short* __restrict__ q,
                                                 const short* __restrict__ k,
                                                 const short* __restrict__ vt,
                                                 short* __restrict__ ao) {
    __shared__ short Ks[2][64 * 64];   // [kv][hd], XOR-swizzled 16B chunks
    __shared__ short Vts[2][64 * 64];  // [hd][kv], XOR-swizzled
    __shared__ short Ps[64 * 64];      // [q][kv], XOR-swizzled, wave-private rows
    __shared__ float sums[64];
    const int tid = threadIdx.x;
    const int lane = tid & 63, w = tid >> 6;
    const int bid = (int)blockIdx.x;
    const int xcd = bid & 7, slot = bid >> 3;
    const int bh = xcd * 4 + (slot & 3);     // pin 4 heads per XCD
    const int qpair = slot >> 2;             // 0..15
    const size_t base = (size_t)bh * S_ * HD_;
    const short* qp = q + base;
    const short* kp = k + base;
    const short* vp = vt + base;       // [64][2048]
    const int bb = bh >> 4, hh = bh & 15;
    const int wrow = w * 16;           // wave's 16 q-rows within the 64-row tile

    for (int half = 0; half < 2; ++half) {
        const int qt = (half == 0) ? qpair : 31 - qpair;
        const int q0 = qt * 64;
        short8 qf[2];
        #pragma unroll
        for (int ks = 0; ks < 2; ++ks)
            qf[ks] = *(const short8*)&qp[(size_t)(q0 + wrow + (lane & 15)) * HD_
                                         + ks * 32 + (lane >> 4) * 8];
        float4v accO[4];
        float lsum = 0.f;
        #pragma unroll
        for (int n = 0; n < 4; ++n) accO[n] = (float4v){0.f, 0.f, 0.f, 0.f};

        const int nkb = qt + 1;
        __syncthreads();                  // prior-half readers of K/V buffers done
        // prologue stage of kv-block 0 into buffer 0
        #pragma unroll
        for (int j = 0; j < 2; ++j) {
            const int g = (w * 2 + j) * 64 + lane;
            const int r = g >> 3, cs = g & 7;
            const int co = (cs ^ (r & 7)) << 3;
            GLD16(kp + (size_t)r * HD_ + co, &Ks[0][g * 8]);
            GLD16(vp + (size_t)r * S_ + co,  &Vts[0][g * 8]);
        }
        int cur = 0;
        for (int kb = 0; kb < nkb; ++kb) {
            const int kv0 = kb * 64;
            __syncthreads();              // stage(cur) complete; prev readers done
            if (kb + 1 < nkb) {
                const int kv1 = kv0 + 64;
                #pragma unroll
                for (int j = 0; j < 2; ++j) {
                    const int g = (w * 2 + j) * 64 + lane;
                    const int r = g >> 3, cs = g & 7;
                    const int co = (cs ^ (r & 7)) << 3;
                    GLD16(kp + (size_t)(kv1 + r) * HD_ + co, &Ks[cur ^ 1][g * 8]);
                    GLD16(vp + (size_t)r * S_ + kv1 + co,    &Vts[cur ^ 1][g * 8]);
                }
            }
            const bool diag = (kb == qt);
            const int qg = q0 + wrow + (lane & 15);
            const int prow = wrow + (lane & 15);
            float4v accS[4];
            #pragma unroll
            for (int n = 0; n < 4; ++n) accS[n] = (float4v){0.f, 0.f, 0.f, 0.f};
            __builtin_amdgcn_s_setprio(1);

            auto qk_n = [&](int n) {
                #pragma unroll
                for (int ks = 0; ks < 2; ++ks) {
                    const int rowk = n * 16 + (lane & 15);
                    const int ch = ks * 4 + (lane >> 4);
                    const short8 kf = *(const short8*)&Ks[cur][rowk * 64 + ((ch ^ (rowk & 7)) << 3)];
                    accS[n] = __builtin_amdgcn_mfma_f32_16x16x32_bf16(kf, qf[ks], accS[n], 0, 0, 0);
                }
            };
            auto sm_n = [&](int n) {
                const int kvb = kv0 + n * 16 + ((lane >> 4) << 2);
                float p[4];
                if (diag) {
                    const int dlim = qg - kvb;
                    #pragma unroll
                    for (int ri = 0; ri < 4; ++ri)
                        p[ri] = (ri <= dlim) ? fast_exp2(accS[n][ri]) : 0.f;
                } else {
                    #pragma unroll
                    for (int ri = 0; ri < 4; ++ri)
                        p[ri] = fast_exp2(accS[n][ri]);
                }
                lsum += (p[0] + p[1]) + (p[2] + p[3]);
                const unsigned lo = cvt_pk_bf16(p[0], p[1]);
                const unsigned hi = cvt_pk_bf16(p[2], p[3]);
                const int col = n * 16 + ((lane >> 4) << 2);
                const int ch = col >> 3;
                const int addr = prow * 64 + ((ch ^ (prow & 7)) << 3) + (col & 7);
                *(uint2*)&Ps[addr] = (uint2){lo, hi};
            };
            auto pv_ks = [&](int ks) {
                const int chp = ks * 4 + (lane >> 4);
                const short8 pf = *(const short8*)&Ps[prow * 64 + ((chp ^ (prow & 7)) << 3)];
                #pragma unroll
                for (int n = 0; n < 4; ++n) {
                    const int vrow = n * 16 + (lane & 15);
                    const int ch = ks * 4 + (lane >> 4);
                    const short8 vf = *(const short8*)&Vts[cur][vrow * 64 + ((ch ^ (vrow & 7)) << 3)];
                    accO[n] = __builtin_amdgcn_mfma_f32_16x16x32_bf16(pf, vf, accO[n], 0, 0, 0);
                }
            };

            // interleaved: VALU blocks overlap async MFMA clusters
            qk_n(0); qk_n(1);
            sm_n(0); sm_n(1);
            qk_n(2); qk_n(3);
            pv_ks(0);
            sm_n(2); sm_n(3);
            pv_ks(1);

            __builtin_amdgcn_s_setprio(0);
            cur ^= 1;
        }
        // row sums: 4 lanes share a q-row -> 2 shuffles, park in LDS (wave-private rows)
        {
            float t = lsum;
            t += __shfl_xor(t, 16);
            t += __shfl_xor(t, 32);
            if (lane < 16) sums[wrow + lane] = t;
        }
        #pragma unroll
        for (int ri = 0; ri < 4; ++ri) {
            const int lrow = wrow + ((lane >> 4) << 2) + ri;
            const float inv = 1.f / sums[lrow];
            const int grow = q0 + lrow;
            #pragma unroll
            for (int n = 0; n < 4; ++n) {
                const int col = hh * 64 + n * 16 + (lane & 15);
                ao[((size_t)(bb * S_ + grow)) * D_ + col] = f2bf(accO[n][ri] * inv);
            }
        }
    }
}

// ---------- GEMM2: out(b,d,s) = (W2t @ ao^T), XCD-rectangle swizzle, 8-wave BK=64 ----
__global__ __launch_bounds__(512) void gemm_out_mfma(const short* __restrict__ W2t,
                                                     const short* __restrict__ ao,
                                                     float* __restrict__ out) {
    __shared__ short As[128 * 64], Bs[128 * 64];
    float4v acc[2][4];
    #pragma unroll
    for (int m = 0; m < 2; ++m)
        #pragma unroll
        for (int n = 0; n < 4; ++n) acc[m][n] = (float4v){0.f, 0.f, 0.f, 0.f};
    const int bid = (int)blockIdx.x;
    const int xcd = bid & 7, r = bid >> 3;            // r in 0..31
    const int mt = (xcd & 1) * 4 + (r & 3);           // d-tile 0..7
    const int nt = (xcd >> 1) * 8 + (r >> 2);         // bs-tile 0..31
    const int m0 = mt * 128, n0 = nt * 128;           // m: d index, n: b*s index
    gemm_core8(W2t, ao, m0, n0, As, Bs, acc);
    const int lane = threadIdx.x & 63, w = threadIdx.x >> 6;
    const int wr = (w >> 1) * 32, wc = (w & 1) * 64;
    #pragma unroll
    for (int m = 0; m < 2; ++m) {
        #pragma unroll
        for (int ri = 0; ri < 4; ++ri) {
            const int grow = m0 + wr + m * 16 + (lane >> 4) * 4 + ri;   // d index
            #pragma unroll
            for (int n = 0; n < 4; ++n) {
                const int gcol = n0 + wc + n * 16 + (lane & 15);        // b*s index
                const int bb = gcol >> 11, ss = gcol & (S_ - 1);
                out[(size_t)bb * D_ * S_ + (size_t)grow * S_ + ss] = acc[m][n][ri];
            }
        }
    }
}

extern "C" void kernel_launch(void* const* d_in, const int* in_sizes, int n_in,
                              void* d_out, int out_size, void* d_ws, size_t ws_size,
                              hipStream_t stream) {
    const float* x  = (const float*)d_in[0];
    const float* W1 = (const float*)d_in[1];
    const float* W2 = (const float*)d_in[2];
    float* out = (float*)d_out;

    short* xt  = (short*)d_ws;                          // 4096x1024
    short* W1t = xt  + (size_t)M_ * D_;                 // 3072x1024
    short* W2t = W1t + (size_t)D3_ * D_;                // 1024x1024
    short* q   = W2t + (size_t)D_ * D_;                 // (b,h,s,hd), pre-scaled
    short* kk  = q   + (size_t)B_ * H_ * S_ * HD_;
    short* vt  = kk  + (size_t)B_ * H_ * S_ * HD_;      // (b,h,hd,s)
    short* ao  = vt  + (size_t)B_ * H_ * S_ * HD_;      // (b,s,d)

    transpose_cvt_all<<<dim3(2048), 256, 0, stream>>>(x, xt, W1, W1t, W2, W2t);
    gemm_qkv_mfma<<<dim3(768), 512, 0, stream>>>(xt, W1t, q, kk, vt);
    attn_mfma<<<dim3(512), 256, 0, stream>>>(q, kk, vt, ao);
    gemm_out_mfma<<<dim3(256), 512, 0, stream>>>(W2t, ao, out);
}

// Round 25
// 109.422 us; speedup vs baseline: 1.0077x; 1.0077x over previous
//
#include <hip/hip_runtime.h>
#include <math.h>

// Problem constants (SelfAttention: b=2, d=1024, s=2048, h=16, hd=64)
#define B_  2
#define D_  1024
#define S_  2048
#define H_  16
#define HD_ 64
#define D3_ 3072
#define M_  4096   // B_*S_

typedef __attribute__((ext_vector_type(8))) short short8;
typedef __attribute__((ext_vector_type(4))) float float4v;

__device__ __forceinline__ short f2bf(float f) {
    unsigned u = __builtin_bit_cast(unsigned, f);
    unsigned r = (u + 0x7FFFu + ((u >> 16) & 1u)) >> 16;   // RNE
    return (short)r;
}

__device__ __forceinline__ unsigned cvt_pk_bf16(float lo, float hi) {
    unsigned r;
    asm("v_cvt_pk_bf16_f32 %0, %1, %2" : "=v"(r) : "v"(lo), "v"(hi));
    return r;
}

__device__ __forceinline__ float fast_exp2(float x) {
    float r;
    asm("v_exp_f32 %0, %1" : "=v"(r) : "v"(x));
    return r;
}

#define GLD16(gsrc, ldst)                                                      \
    __builtin_amdgcn_global_load_lds(                                          \
        (const __attribute__((address_space(1))) void*)(gsrc),                 \
        (__attribute__((address_space(3))) void*)(ldst), 16, 0, 0)

// ---------- merged transpose + fp32->bf16 convert for x, W1, W2 (R16-exact) ----
__global__ __launch_bounds__(256) void transpose_cvt_all(const float* __restrict__ x,
                                                         short* __restrict__ xt,
                                                         const float* __restrict__ W1,
                                                         short* __restrict__ W1t,
                                                         const float* __restrict__ W2,
                                                         short* __restrict__ W2t) {
    __shared__ short t[64][66];          // +2 pad: write-side reads are 2-way only
    const int bid = (int)blockIdx.x;
    const float* in;
    short* out;
    int C, R, rb, cb;
    if (bid < 1024) {
        const int z = bid >> 9, tt = bid & 511;
        R = D_; C = S_;
        cb = tt & 31; rb = tt >> 5;
        in = x + (size_t)z * D_ * S_;
        out = xt + (size_t)z * D_ * S_;
    } else if (bid < 1792) {
        const int tt = bid - 1024;
        R = D_; C = D3_;
        cb = tt % 48; rb = tt / 48;
        in = W1; out = W1t;
    } else {
        const int tt = bid - 1792;
        R = D_; C = D_;
        cb = tt & 15; rb = tt >> 4;
        in = W2; out = W2t;
    }
    const int r0 = rb * 64, c0 = cb * 64;
    const int tx = threadIdx.x & 31, ty = threadIdx.x >> 5;
    #pragma unroll
    for (int i = ty; i < 64; i += 8) {
        const float2 v = *(const float2*)&in[(size_t)(r0 + i) * C + c0 + tx * 2];
        t[i][tx * 2]     = f2bf(v.x);
        t[i][tx * 2 + 1] = f2bf(v.y);
    }
    __syncthreads();
    #pragma unroll
    for (int j = ty; j < 64; j += 8) {
        short2 v;
        v.x = t[tx * 2][j];
        v.y = t[tx * 2 + 1][j];
        *(short2*)&out[(size_t)(c0 + j) * R + r0 + tx * 2] = v;
    }
}

// ---------- MFMA GEMM core: m97 structure + R15 swizzle, 8 waves (R20-exact) ----
__device__ __forceinline__ void gemm_core8(const short* __restrict__ A,
                                           const short* __restrict__ Bt,
                                           int m0, int n0,
                                           short* As, short* Bs,
                                           float4v acc[2][4]) {
    const int tid = threadIdx.x;
    const int lane = tid & 63, w = tid >> 6;                 // 0..7
    const int wr = (w >> 1) * 32, wc = (w & 1) * 64;
    const int srow = lane >> 2;                              // row within 16-row chunk
    const int scol = ((lane & 3) ^ ((srow >> 1) & 3)) * 8;   // inverse-swizzled src col
    const int rr = lane & 15;                                // fragment row (mod 16)
    const int kc = ((lane >> 4) ^ ((rr >> 1) & 3)) * 8;      // swizzled read chunk
    for (int k0 = 0; k0 < 1024; k0 += 32) {
        GLD16(A  + (size_t)(m0 + w * 16 + srow) * 1024 + k0 + scol,
              As + w * 512 + lane * 8);
        GLD16(Bt + (size_t)(n0 + w * 16 + srow) * 1024 + k0 + scol,
              Bs + w * 512 + lane * 8);
        __syncthreads();
        short8 a[2], b[4];
        #pragma unroll
        for (int m = 0; m < 2; ++m)
            a[m] = *(const short8*)&As[(wr + m * 16 + rr) * 32 + kc];
        #pragma unroll
        for (int n = 0; n < 4; ++n)
            b[n] = *(const short8*)&Bs[(wc + n * 16 + rr) * 32 + kc];
        #pragma unroll
        for (int m = 0; m < 2; ++m)
            #pragma unroll
            for (int n = 0; n < 4; ++n)
                acc[m][n] = __builtin_amdgcn_mfma_f32_16x16x32_bf16(a[m], b[n], acc[m][n], 0, 0, 0);
        __syncthreads();
    }
}

// ---------- GEMM1: qkv = xt @ W1t^T; XCD-rectangle swizzle; 8-wave (R20-exact) ----
__global__ __launch_bounds__(512) void gemm_qkv_mfma(const short* __restrict__ xt,
                                                     const short* __restrict__ W1t,
                                                     short* __restrict__ q,
                                                     short* __restrict__ kk,
                                                     short* __restrict__ vt) {
    __shared__ short As[128 * 32], Bs[128 * 32];
    float4v acc[2][4];
    #pragma unroll
    for (int m = 0; m < 2; ++m)
        #pragma unroll
        for (int n = 0; n < 4; ++n) acc[m][n] = (float4v){0.f, 0.f, 0.f, 0.f};
    const int bid = (int)blockIdx.x;
    const int xcd = bid & 7, r = bid >> 3;        // r in 0..95
    const int mt = (xcd & 3) * 8 + (r & 7);       // m-tile 0..31
    const int nt = (xcd >> 2) * 12 + (r >> 3);    // n-tile 0..23
    const int m0 = mt * 128, n0 = nt * 128;
    gemm_core8(xt, W1t, m0, n0, As, Bs, acc);
    const int lane = threadIdx.x & 63, w = threadIdx.x >> 6;
    const int wr = (w >> 1) * 32, wc = (w & 1) * 64;
    const float qscale = 0.125f * 1.44269504f;   // fold softmax scale*log2(e) into q
    #pragma unroll
    for (int n = 0; n < 4; ++n) {
        const int gcol = n0 + wc + n * 16 + (lane & 15);
        const int which = gcol >> 10, hh = (gcol >> 6) & 15, hd = gcol & 63;
        #pragma unroll
        for (int m = 0; m < 2; ++m) {
            #pragma unroll
            for (int ri = 0; ri < 4; ++ri) {
                const int grow = m0 + wr + m * 16 + (lane >> 4) * 4 + ri;
                const int bb = grow >> 11, ss = grow & (S_ - 1);
                float av = acc[m][n][ri];
                if (which == 0) av *= qscale;
                const short v = f2bf(av);
                if (which == 0)      q [((size_t)(bb * H_ + hh) * S_ + ss) * HD_ + hd] = v;
                else if (which == 1) kk[((size_t)(bb * H_ + hh) * S_ + ss) * HD_ + hd] = v;
                else                 vt[((size_t)(bb * H_ + hh) * HD_ + hd) * S_ + ss] = v;
            }
        }
    }
}

// ---------- Flash attention: R18 structure + intra-layer softmax||PV interleave ----
// Wave-local reorder only (no sync changes): QK(n=0,1) -> softmax(0,1) ->
// QK(n=2,3) -> PV(ks=0, consumes P kv 0..31) -> softmax(2,3) -> PV(ks=1).
__global__ __launch_bounds__(256) void attn_mfma(const short* __restrict__ q,
                                                 const short* __restrict__ k,
                                                 const short* __restrict__ vt,
                                                 short* __restrict__ ao) {
    __shared__ short Ks[2][64 * 64];   // [kv][hd], XOR-swizzled 16B chunks
    __shared__ short Vts[2][64 * 64];  // [hd][kv], XOR-swizzled
    __shared__ short Ps[64 * 64];      // [q][kv], XOR-swizzled, wave-private rows
    __shared__ float sums[64];
    const int tid = threadIdx.x;
    const int lane = tid & 63, w = tid >> 6;
    const int bid = (int)blockIdx.x;
    const int xcd = bid & 7, slot = bid >> 3;
    const int bh = xcd * 4 + (slot & 3);     // pin 4 heads per XCD
    const int qpair = slot >> 2;             // 0..15
    const size_t base = (size_t)bh * S_ * HD_;
    const short* qp = q + base;
    const short* kp = k + base;
    const short* vp = vt + base;       // [64][2048]
    const int bb = bh >> 4, hh = bh & 15;
    const int wrow = w * 16;           // wave's 16 q-rows within the 64-row tile

    for (int half = 0; half < 2; ++half) {
        const int qt = (half == 0) ? qpair : 31 - qpair;
        const int q0 = qt * 64;
        short8 qf[2];
        #pragma unroll
        for (int ks = 0; ks < 2; ++ks)
            qf[ks] = *(const short8*)&qp[(size_t)(q0 + wrow + (lane & 15)) * HD_
                                         + ks * 32 + (lane >> 4) * 8];
        float4v accO[4];
        float lsum = 0.f;
        #pragma unroll
        for (int n = 0; n < 4; ++n) accO[n] = (float4v){0.f, 0.f, 0.f, 0.f};

        const int nkb = qt + 1;
        __syncthreads();                  // prior-half readers of K/V buffers done
        // prologue stage of kv-block 0 into buffer 0
        #pragma unroll
        for (int j = 0; j < 2; ++j) {
            const int g = (w * 2 + j) * 64 + lane;
            const int r = g >> 3, cs = g & 7;
            const int co = (cs ^ (r & 7)) << 3;
            GLD16(kp + (size_t)r * HD_ + co, &Ks[0][g * 8]);
            GLD16(vp + (size_t)r * S_ + co,  &Vts[0][g * 8]);
        }
        int cur = 0;
        for (int kb = 0; kb < nkb; ++kb) {
            const int kv0 = kb * 64;
            __syncthreads();              // stage(cur) complete; prev readers done
            if (kb + 1 < nkb) {
                const int kv1 = kv0 + 64;
                #pragma unroll
                for (int j = 0; j < 2; ++j) {
                    const int g = (w * 2 + j) * 64 + lane;
                    const int r = g >> 3, cs = g & 7;
                    const int co = (cs ^ (r & 7)) << 3;
                    GLD16(kp + (size_t)(kv1 + r) * HD_ + co, &Ks[cur ^ 1][g * 8]);
                    GLD16(vp + (size_t)r * S_ + kv1 + co,    &Vts[cur ^ 1][g * 8]);
                }
            }
            const bool diag = (kb == qt);
            const int qg = q0 + wrow + (lane & 15);
            const int prow = wrow + (lane & 15);
            float4v accS[4];
            #pragma unroll
            for (int n = 0; n < 4; ++n) accS[n] = (float4v){0.f, 0.f, 0.f, 0.f};
            __builtin_amdgcn_s_setprio(1);

            auto qk_n = [&](int n) {
                #pragma unroll
                for (int ks = 0; ks < 2; ++ks) {
                    const int rowk = n * 16 + (lane & 15);
                    const int ch = ks * 4 + (lane >> 4);
                    const short8 kf = *(const short8*)&Ks[cur][rowk * 64 + ((ch ^ (rowk & 7)) << 3)];
                    accS[n] = __builtin_amdgcn_mfma_f32_16x16x32_bf16(kf, qf[ks], accS[n], 0, 0, 0);
                }
            };
            auto sm_n = [&](int n) {
                const int kvb = kv0 + n * 16 + ((lane >> 4) << 2);
                float p[4];
                if (diag) {
                    const int dlim = qg - kvb;
                    #pragma unroll
                    for (int ri = 0; ri < 4; ++ri)
                        p[ri] = (ri <= dlim) ? fast_exp2(accS[n][ri]) : 0.f;
                } else {
                    #pragma unroll
                    for (int ri = 0; ri < 4; ++ri)
                        p[ri] = fast_exp2(accS[n][ri]);
                }
                lsum += (p[0] + p[1]) + (p[2] + p[3]);
                const unsigned lo = cvt_pk_bf16(p[0], p[1]);
                const unsigned hi = cvt_pk_bf16(p[2], p[3]);
                const int col = n * 16 + ((lane >> 4) << 2);
                const int ch = col >> 3;
                const int addr = prow * 64 + ((ch ^ (prow & 7)) << 3) + (col & 7);
                *(uint2*)&Ps[addr] = (uint2){lo, hi};
            };
            auto pv_ks = [&](int ks) {
                const int chp = ks * 4 + (lane >> 4);
                const short8 pf = *(const short8*)&Ps[prow * 64 + ((chp ^ (prow & 7)) << 3)];
                #pragma unroll
                for (int n = 0; n < 4; ++n) {
                    const int vrow = n * 16 + (lane & 15);
                    const int ch = ks * 4 + (lane >> 4);
                    const short8 vf = *(const short8*)&Vts[cur][vrow * 64 + ((ch ^ (vrow & 7)) << 3)];
                    accO[n] = __builtin_amdgcn_mfma_f32_16x16x32_bf16(pf, vf, accO[n], 0, 0, 0);
                }
            };

            // interleaved: VALU blocks overlap async MFMA clusters
            qk_n(0); qk_n(1);
            sm_n(0); sm_n(1);
            qk_n(2); qk_n(3);
            pv_ks(0);
            sm_n(2); sm_n(3);
            pv_ks(1);

            __builtin_amdgcn_s_setprio(0);
            cur ^= 1;
        }
        // row sums: 4 lanes share a q-row -> 2 shuffles, park in LDS (wave-private rows)
        {
            float t = lsum;
            t += __shfl_xor(t, 16);
            t += __shfl_xor(t, 32);
            if (lane < 16) sums[wrow + lane] = t;
        }
        #pragma unroll
        for (int ri = 0; ri < 4; ++ri) {
            const int lrow = wrow + ((lane >> 4) << 2) + ri;
            const float inv = 1.f / sums[lrow];
            const int grow = q0 + lrow;
            #pragma unroll
            for (int n = 0; n < 4; ++n) {
                const int col = hh * 64 + n * 16 + (lane & 15);
                ao[((size_t)(bb * S_ + grow)) * D_ + col] = f2bf(accO[n][ri] * inv);
            }
        }
    }
}

// ---------- GEMM2: out(b,d,s) = (W2t @ ao^T), XCD-rectangle swizzle, 8-wave ----
__global__ __launch_bounds__(512) void gemm_out_mfma(const short* __restrict__ W2t,
                                                     const short* __restrict__ ao,
                                                     float* __restrict__ out) {
    __shared__ short As[128 * 32], Bs[128 * 32];
    float4v acc[2][4];
    #pragma unroll
    for (int m = 0; m < 2; ++m)
        #pragma unroll
        for (int n = 0; n < 4; ++n) acc[m][n] = (float4v){0.f, 0.f, 0.f, 0.f};
    const int bid = (int)blockIdx.x;
    const int xcd = bid & 7, r = bid >> 3;            // r in 0..31
    const int mt = (xcd & 1) * 4 + (r & 3);           // d-tile 0..7
    const int nt = (xcd >> 1) * 8 + (r >> 2);         // bs-tile 0..31
    const int m0 = mt * 128, n0 = nt * 128;           // m: d index, n: b*s index
    gemm_core8(W2t, ao, m0, n0, As, Bs, acc);
    const int lane = threadIdx.x & 63, w = threadIdx.x >> 6;
    const int wr = (w >> 1) * 32, wc = (w & 1) * 64;
    #pragma unroll
    for (int m = 0; m < 2; ++m) {
        #pragma unroll
        for (int ri = 0; ri < 4; ++ri) {
            const int grow = m0 + wr + m * 16 + (lane >> 4) * 4 + ri;   // d index
            #pragma unroll
            for (int n = 0; n < 4; ++n) {
                const int gcol = n0 + wc + n * 16 + (lane & 15);        // b*s index
                const int bb = gcol >> 11, ss = gcol & (S_ - 1);
                out[(size_t)bb * D_ * S_ + (size_t)grow * S_ + ss] = acc[m][n][ri];
            }
        }
    }
}

extern "C" void kernel_launch(void* const* d_in, const int* in_sizes, int n_in,
                              void* d_out, int out_size, void* d_ws, size_t ws_size,
                              hipStream_t stream) {
    const float* x  = (const float*)d_in[0];
    const float* W1 = (const float*)d_in[1];
    const float* W2 = (const float*)d_in[2];
    float* out = (float*)d_out;

    short* xt  = (short*)d_ws;                          // 4096x1024
    short* W1t = xt  + (size_t)M_ * D_;                 // 3072x1024
    short* W2t = W1t + (size_t)D3_ * D_;                // 1024x1024
    short* q   = W2t + (size_t)D_ * D_;                 // (b,h,s,hd), pre-scaled
    short* kk  = q   + (size_t)B_ * H_ * S_ * HD_;
    short* vt  = kk  + (size_t)B_ * H_ * S_ * HD_;      // (b,h,hd,s)
    short* ao  = vt  + (size_t)B_ * H_ * S_ * HD_;      // (b,s,d)

    transpose_cvt_all<<<dim3(2048), 256, 0, stream>>>(x, xt, W1, W1t, W2, W2t);
    gemm_qkv_mfma<<<dim3(768), 512, 0, stream>>>(xt, W1t, q, kk, vt);
    attn_mfma<<<dim3(512), 256, 0, stream>>>(q, kk, vt, ao);
    gemm_out_mfma<<<dim3(256), 512, 0, stream>>>(W2t, ao, out);
}